// Round 11
// baseline (6365.900 us; speedup 1.0000x reference)
//
#include <hip/hip_runtime.h>
#include <hip/hip_fp16.h>

#define BB 64
#define SS 1024
#define MEL 60
#define HH 180
#define G4 720    // 4*H
#define GP 192    // per-gate padded hidden
#define G4P 768   // 4*GP
#define NKS 6     // k-steps of 32 (K padded to 192)
#define NL 4
#define NPOST 8192
#define NOUT 300
#define NOUTP 320
#define KSPL 16
#define TT 128
#define CH 64
#define NCH (SS / CH)
#define NKP 96    // k-pair slots for wih (192/2)
#define HROW 216  // padded LDS h-row (halves)
#define NPAIR (16 * HH)   // 2880 (b,hid) pairs per WG

typedef _Float16 f16x8 __attribute__((ext_vector_type(8)));
typedef float f32x4 __attribute__((ext_vector_type(4)));

#if defined(__has_builtin)
#if __has_builtin(__builtin_amdgcn_fdot2)
#define HAVE_FDOT2 1
#endif
#endif
#ifndef HAVE_FDOT2
#define HAVE_FDOT2 0
#endif

__device__ __forceinline__ float fdot2u(unsigned int w, unsigned int h, float acc) {
#if HAVE_FDOT2
    typedef _Float16 h2_t __attribute__((ext_vector_type(2)));
    union U { unsigned int u; h2_t v; };
    U a, b;
    a.u = w; b.u = h;
    return __builtin_amdgcn_fdot2(a.v, b.v, acc, false);
#else
    __half2 aw = *reinterpret_cast<const __half2*>(&w);
    __half2 ah = *reinterpret_cast<const __half2*>(&h);
    acc += __half2float(__low2half(aw)) * __half2float(__low2half(ah));
    acc += __half2float(__high2half(aw)) * __half2float(__high2half(ah));
    return acc;
#endif
}

union WU { uint4 u; f16x8 f; };

// ---------------- prep ----------------
// wmf[l][g 48][ks 6][lane 64] = 8 f16: g = q*12 + hg; col hid = hg*16 + (lane&15);
// elem j = whh[l][q*180 + hid][k], k = ks*32 + 8*(lane>>4) + j; zero-padded.
__global__ void prep_wmf(const float* __restrict__ whh, uint4* __restrict__ wmf) {
    int idx = blockIdx.x * blockDim.x + threadIdx.x;
    int total = NL * 48 * NKS * 64;
    if (idx >= total) return;
    int l = idx / (48 * NKS * 64);
    int r1 = idx % (48 * NKS * 64);
    int g = r1 / (NKS * 64);
    int r2 = r1 % (NKS * 64);
    int ks = r2 / 64, lane = r2 % 64;
    int q = g / 12, hg = g % 12;
    int hid = hg * 16 + (lane & 15);
    unsigned short v[8];
    #pragma unroll
    for (int j = 0; j < 8; ++j) {
        int k = ks * 32 + ((lane >> 4) << 3) + j;
        float f = (hid < HH && k < HH) ? whh[((size_t)l * G4 + q * HH + hid) * HH + k] : 0.f;
        v[j] = __half_as_ushort(__float2half(f));
    }
    uint4 u;
    u.x = (unsigned)v[0] | ((unsigned)v[1] << 16);
    u.y = (unsigned)v[2] | ((unsigned)v[3] << 16);
    u.z = (unsigned)v[4] | ((unsigned)v[5] << 16);
    u.w = (unsigned)v[6] | ((unsigned)v[7] << 16);
    wmf[idx] = u;
}

// wihP: [l][col 768][kp 96] uint = packed f16 pair along k; col = q*192 + hid
__global__ void prep_wihP(const float* __restrict__ wih0, const float* __restrict__ wih_rest,
                          unsigned int* __restrict__ w) {
    int idx = blockIdx.x * blockDim.x + threadIdx.x;
    int total = NL * G4P * NKP;
    if (idx >= total) return;
    int l = idx / (G4P * NKP);
    int r = idx % (G4P * NKP);
    int col = r / NKP, kp = r % NKP;
    int q = col / GP, hid = col % GP;
    int K = (l == 0) ? MEL : HH;
    float a = 0.f, b = 0.f;
    if (hid < HH && 2 * kp < K) {
        int g = q * HH + hid;
        const float* src = (l == 0) ? (wih0 + (size_t)g * MEL)
                                    : (wih_rest + ((size_t)(l - 1) * G4 + g) * HH);
        a = src[2 * kp]; b = src[2 * kp + 1];
    }
    __half2 h2 = __floats2half2_rn(a, b);
    w[idx] = *(unsigned int*)&h2;
}

__global__ void prep_bsumP(const float* __restrict__ bih, const float* __restrict__ bhh,
                           float* __restrict__ bsP) {
    int idx = blockIdx.x * blockDim.x + threadIdx.x;
    if (idx >= NL * G4P) return;
    int l = idx / G4P, col = idx % G4P;
    int q = col / GP, hid = col % GP;
    float v = 0.f;
    if (hid < HH) {
        int g = l * G4 + q * HH + hid;
        v = bih[g] + bhh[g];
    }
    bsP[idx] = v;
}

// ---------------- mel smooth residual block ----------------
template <typename TIN>
__global__ __launch_bounds__(256) void mel_block(const TIN* __restrict__ in,
                                                 __half* __restrict__ out,
                                                 const float* __restrict__ w,
                                                 const float* __restrict__ bias) {
    __shared__ float xt[TT + 4][MEL];
    __shared__ float ws[900];
    __shared__ float bs[MEL];
    int bb = blockIdx.x;
    int t0 = blockIdx.y * TT;
    int tid = threadIdx.x;
    const TIN* inb = in + (size_t)bb * SS * MEL;
    for (int idx = tid; idx < (TT + 4) * MEL; idx += 256) {
        int tt = idx / MEL, ch = idx % MEL;
        int t = t0 + tt - 2;
        xt[tt][ch] = (t >= 0 && t < SS) ? (float)inb[(size_t)t * MEL + ch] : 0.f;
    }
    for (int idx = tid; idx < 900; idx += 256) ws[idx] = w[idx];
    if (tid < MEL) bs[tid] = bias[(tid % 3) * 20 + tid / 3];
    __syncthreads();
    for (int idx = tid; idx < TT * MEL; idx += 256) {
        int tt = idx / MEL, ch = idx % MEL;
        int i = ch / 3, j = ch % 3;
        int qb = 3 * i + (j - 1);
        float acc = bs[ch];
        #pragma unroll
        for (int c = 0; c < 3; ++c) {
            int q = qb + c;
            if (q >= 0 && q < MEL) {
                const float* wp = ws + ((j * 20 + i) * 3 + c) * 5;
                #pragma unroll
                for (int k = 0; k < 5; ++k) acc += xt[tt + k][q] * wp[k];
            }
        }
        out[(size_t)bb * SS * MEL + (size_t)(t0 + tt) * MEL + ch] =
            __float2half(acc + xt[tt + 2][ch]);
    }
}

// ---------------- fused wave step: scan(wave w) + gemm(wave w+1 inputs) ----------------
struct WaveArgs {
    // scan jobs (16 batches per WG, 4 WGs per job)
    const __half* spre[NL];   // [CH][64][768] f16
    const uint4*  swmf[NL];
    __half*       shout[NL];
    float*        shst[NL];
    float*        scst[NL];
    int           st0[NL];
    // gemm jobs: pre[t][b][col 768] = A[b][t][:] . W[col] + bs[col]
    const __half* gA[NL];
    const unsigned int* gW[NL];
    const float*  gbs[NL];
    __half*       gC[NL];
    int           gK[NL];
    int           gKT[NL];
    int           gt0[NL];
    int           nS;
    int           nG;
};

__global__ __launch_bounds__(512) __attribute__((amdgpu_waves_per_eu(2, 2)))
void wave_step(WaveArgs wa) {
    __shared__ __align__(16) unsigned short hsb[2][16][HROW];  // 13.8 KB
    __shared__ float gates[48 * 256];                          // 49 KB  [g][b 16][col 16]
    __shared__ unsigned int gAs[2][8][68];                     // gemm staging
    __shared__ unsigned int gWs[2][8][68];
    int blk = blockIdx.x;
    int tid = threadIdx.x;

    if (blk < wa.nS * 4) {
        // ================= scan =================
        int j = blk >> 2, bg = blk & 3;
        int b0 = bg << 4;
        int wv = tid >> 6, lane = tid & 63;
        int r0 = lane >> 4, cl = lane & 15;
        int t0 = wa.st0[j];
        const __half* preb = wa.spre[j];
        __half* hout = wa.shout[j];
        float* hst = wa.shst[j];
        float* cst = wa.scst[j];

        // weights: wave wv owns col-groups 6wv..6wv+5 -> 36 uint4 = 144 VGPRs
        uint4 wfr[6][NKS];
        {
            const uint4* wm = wa.swmf[j];
            #pragma unroll
            for (int i = 0; i < 6; ++i)
                #pragma unroll
                for (int ks = 0; ks < NKS; ++ks)
                    wfr[i][ks] = wm[((6 * wv + i) * NKS + ks) * 64 + lane];
        }
        #pragma unroll
        for (int i = 0; i < 6; ++i)
            #pragma unroll
            for (int ks = 0; ks < NKS; ++ks)
                asm volatile("" : "+v"(wfr[i][ks].x), "+v"(wfr[i][ks].y),
                                  "+v"(wfr[i][ks].z), "+v"(wfr[i][ks].w));

        // per-thread nonlin pair assignments (6 each): idx = tid + 512k
        int goff[6], poff[6], hwo[6];
        unsigned hob[6];
        #pragma unroll
        for (int k = 0; k < 6; ++k) {
            int idx = tid + (k << 9);
            int hid = idx % HH, bl2 = idx / HH;
            if (idx >= NPAIR) { hid = 0; bl2 = 0; }
            goff[k] = (hid >> 4) * 256 + bl2 * 16 + (hid & 15);
            poff[k] = bl2 * G4P + hid;
            hwo[k]  = bl2 * HROW + hid;
            hob[k]  = (unsigned)((b0 + bl2) * SS) * HH + hid;
        }
        float c6[6];
        #pragma unroll
        for (int k = 0; k < 6; ++k) {
            int idx = tid + (k << 9);
            float cv = 0.f;
            if (idx < NPAIR && t0 > 0) {
                int hid = idx % HH, bl2 = idx / HH;
                cv = cst[(size_t)(b0 + bl2) * HH + hid];
            }
            c6[k] = cv;
        }
        // init LDS h buffers (pad of both buffers zeroed)
        for (int idx = tid; idx < 16 * HROW; idx += 512) {
            int b = idx / HROW, k2 = idx % HROW;
            float hv = 0.f;
            if (t0 > 0 && k2 < HH) hv = hst[(size_t)(b0 + b) * HH + k2];
            hsb[0][b][k2] = __half_as_ushort(__float2half(hv));
            hsb[1][b][k2] = 0;
        }
        __syncthreads();

        const __half* pt = preb + (size_t)b0 * G4P;  // step base (advance by 64*768)
        for (int t = 0; t < CH; ++t) {
            // MFMA phase: A = h (16 batches), B = wfr, D -> gates LDS
            const unsigned short* hrow = &hsb[t & 1][0][0];
            f16x8 hf[NKS];
            #pragma unroll
            for (int ks = 0; ks < NKS; ++ks) {
                WU hu;
                hu.u = *(const uint4*)(hrow + cl * HROW + (ks << 5) + (r0 << 3));
                hf[ks] = hu.f;
            }
            #pragma unroll
            for (int i = 0; i < 6; ++i) {
                f32x4 acc = {0.f, 0.f, 0.f, 0.f};
                #pragma unroll
                for (int ks = 0; ks < NKS; ++ks) {
                    WU wu; wu.u = wfr[i][ks];
                    acc = __builtin_amdgcn_mfma_f32_16x16x32_f16(hf[ks], wu.f, acc, 0, 0, 0);
                }
                float* gt = &gates[(6 * wv + i) * 256 + (r0 << 2) * 16 + cl];
                gt[0] = acc[0]; gt[16] = acc[1]; gt[32] = acc[2]; gt[48] = acc[3];
            }
            __syncthreads();
            // nonlinearity (gates + pre), update c, write h to LDS + hout
            unsigned short* hnx = &hsb[(t + 1) & 1][0][0];
            #pragma unroll
            for (int k = 0; k < 6; ++k) {
                int idx = tid + (k << 9);
                if (idx < NPAIR) {
                    const __half* pp = pt + poff[k];
                    float gi = gates[goff[k]]            + __half2float(pp[0]);
                    float gf = gates[goff[k] + 12 * 256] + __half2float(pp[GP]);
                    float gg = gates[goff[k] + 24 * 256] + __half2float(pp[2 * GP]);
                    float go = gates[goff[k] + 36 * 256] + __half2float(pp[3 * GP]);
                    float si = 1.f / (1.f + __expf(-gi));
                    float sf = 1.f / (1.f + __expf(-gf));
                    float so = 1.f / (1.f + __expf(-go));
                    float tg = 1.f - 2.f / (__expf(2.f * gg) + 1.f);
                    c6[k] = sf * c6[k] + si * tg;
                    float hn = so * (1.f - 2.f / (__expf(2.f * c6[k]) + 1.f));
                    __half hh = __float2half(hn);
                    hnx[hwo[k]] = __half_as_ushort(hh);
                    hout[(size_t)hob[k] + (size_t)(t0 + t) * HH] = hh;
                }
            }
            __syncthreads();
            pt += (size_t)BB * G4P;
        }
        // store states (final h in hsb[0] since CH even)
        #pragma unroll
        for (int k = 0; k < 6; ++k) {
            int idx = tid + (k << 9);
            if (idx < NPAIR) {
                int hid = idx % HH, bl2 = idx / HH;
                cst[(size_t)(b0 + bl2) * HH + hid] = c6[k];
                hst[(size_t)(b0 + bl2) * HH + hid] =
                    __half2float(__ushort_as_half(hsb[0][bl2][hid]));
            }
        }
    } else {
        // ================= gemm =================
        int gblk = blk - wa.nS * 4;
        int j = gblk / (CH * 6);
        int rem = gblk % (CH * 6);
        int tl = rem / 6, yt = rem % 6;
        int vb = tid >> 8, vtid = tid & 255;
        int n0 = (yt * 2 + vb) * 64;
        int K = wa.gK[j], KT = wa.gKT[j];
        int tg = wa.gt0[j] + tl;
        const __half* A = wa.gA[j];
        const unsigned int* Wp = wa.gW[j];
        const float* bs = wa.gbs[j];
        __half* Cb = wa.gC[j] + (size_t)tl * (BB * G4P);
        int tx = vtid & 15, ty = vtid >> 4;
        int kpl = vtid & 7, mg = vtid >> 3;
        float acc[4][4];
        #pragma unroll
        for (int i = 0; i < 4; ++i)
            #pragma unroll
            for (int jn = 0; jn < 4; ++jn) acc[i][jn] = 0.f;

        for (int kt = 0; kt < KT; ++kt) {
            int kp = (kt << 3) + kpl;
            bool kv = (2 * kp < K);
            #pragma unroll
            for (int r = 0; r < 2; ++r) {
                int b = mg + (r << 5);
                gAs[vb][kpl][b] = kv ? *(const unsigned int*)(A + ((size_t)b * SS + tg) * K + 2 * kp) : 0u;
                gWs[vb][kpl][b] = kv ? Wp[(size_t)(n0 + b) * NKP + kp] : 0u;
            }
            __syncthreads();
            #pragma unroll
            for (int k = 0; k < 8; ++k) {
                unsigned int av[4], bv[4];
                #pragma unroll
                for (int i = 0; i < 4; ++i) av[i] = gAs[vb][k][ty + (i << 4)];
                #pragma unroll
                for (int jn = 0; jn < 4; ++jn) bv[jn] = gWs[vb][k][(tx << 2) + jn];
                #pragma unroll
                for (int i = 0; i < 4; ++i)
                    #pragma unroll
                    for (int jn = 0; jn < 4; ++jn) acc[i][jn] = fdot2u(bv[jn], av[i], acc[i][jn]);
            }
            __syncthreads();
        }
        int c0 = n0 + (tx << 2);
        #pragma unroll
        for (int i = 0; i < 4; ++i) {
            int b = ty + (i << 4);
            __half2 h01 = __floats2half2_rn(acc[i][0] + bs[c0], acc[i][1] + bs[c0 + 1]);
            __half2 h23 = __floats2half2_rn(acc[i][2] + bs[c0 + 2], acc[i][3] + bs[c0 + 3]);
            *(__half2*)(Cb + (size_t)b * G4P + c0) = h01;
            *(__half2*)(Cb + (size_t)b * G4P + c0 + 2) = h23;
        }
    }
}

// ---------------- epilogue ----------------
__global__ void gather_last(const __half* __restrict__ hfin, const int* __restrict__ lens,
                            float* __restrict__ last) {
    int idx = blockIdx.x * blockDim.x + threadIdx.x;
    if (idx >= BB * HH) return;
    int b = idx / HH, d = idx % HH;
    int t = lens[b] - 1;
    t = t < 0 ? 0 : (t > SS - 1 ? SS - 1 : t);
    last[idx] = __half2float(hfin[((size_t)b * SS + t) * HH + d]);
}

__global__ __launch_bounds__(256) void post_gemm(const float* __restrict__ A,
                                                 const float* __restrict__ Bw,
                                                 const float* __restrict__ pb,
                                                 float* __restrict__ Cb) {
    __shared__ float As[16][68];
    __shared__ float Bs[16][68];
    int n0 = blockIdx.x * 64;
    int tid = threadIdx.x;
    int kk = tid & 15, q = tid >> 4;
    int tx = tid & 15, ty = tid >> 4;
    float acc[4][4];
    #pragma unroll
    for (int i = 0; i < 4; ++i)
        #pragma unroll
        for (int jj = 0; jj < 4; ++jj) acc[i][jj] = 0.f;
    for (int kt = 0; kt < 12; ++kt) {
        int kidx = kt * 16 + kk;
        bool kval = kidx < HH;
        #pragma unroll
        for (int r = 0; r < 4; ++r)
            As[kk][q + (r << 4)] = kval ? A[(size_t)(q + (r << 4)) * HH + kidx] : 0.f;
        #pragma unroll
        for (int r = 0; r < 4; ++r)
            Bs[kk][q + (r << 4)] = kval ? Bw[(size_t)(n0 + q + (r << 4)) * HH + kidx] : 0.f;
        __syncthreads();
        #pragma unroll
        for (int k = 0; k < 16; ++k) {
            float a[4], bv[4];
            #pragma unroll
            for (int i = 0; i < 4; ++i) a[i] = As[k][ty + (i << 4)];
            #pragma unroll
            for (int jj = 0; jj < 4; ++jj) bv[jj] = Bs[k][(tx << 2) + jj];
            #pragma unroll
            for (int i = 0; i < 4; ++i)
                #pragma unroll
                for (int jj = 0; jj < 4; ++jj) acc[i][jj] = fmaf(a[i], bv[jj], acc[i][jj]);
        }
        __syncthreads();
    }
    #pragma unroll
    for (int i = 0; i < 4; ++i) {
        int m = ty + (i << 4);
        #pragma unroll
        for (int jj = 0; jj < 4; ++jj) {
            int g = n0 + (tx << 2) + jj;
            float v = acc[i][jj] + pb[g];
            Cb[(size_t)m * NPOST + g] = v > 0.f ? v : 0.01f * v;
        }
    }
}

__global__ __launch_bounds__(256) void up_gemm(const float* __restrict__ A,
                                               const float* __restrict__ Bw,
                                               float* __restrict__ part) {
    __shared__ float As[16][68];
    __shared__ float Bs[16][68];
    int n0 = blockIdx.x * 64;
    int k0 = blockIdx.y * (NPOST / KSPL);
    float* Pb = part + (size_t)blockIdx.y * BB * NOUTP;
    int tid = threadIdx.x;
    int kk = tid & 15, q = tid >> 4;
    int tx = tid & 15, ty = tid >> 4;
    float acc[4][4];
    #pragma unroll
    for (int i = 0; i < 4; ++i)
        #pragma unroll
        for (int jj = 0; jj < 4; ++jj) acc[i][jj] = 0.f;
    for (int kt = 0; kt < (NPOST / KSPL) / 16; ++kt) {
        int kidx = k0 + kt * 16 + kk;
        #pragma unroll
        for (int r = 0; r < 4; ++r)
            As[kk][q + (r << 4)] = A[(size_t)(q + (r << 4)) * NPOST + kidx];
        #pragma unroll
        for (int r = 0; r < 4; ++r) {
            int g = n0 + q + (r << 4);
            Bs[kk][q + (r << 4)] = (g < NOUT) ? Bw[(size_t)g * NPOST + kidx] : 0.f;
        }
        __syncthreads();
        #pragma unroll
        for (int k = 0; k < 16; ++k) {
            float a[4], bv[4];
            #pragma unroll
            for (int i = 0; i < 4; ++i) a[i] = As[k][ty + (i << 4)];
            #pragma unroll
            for (int jj = 0; jj < 4; ++jj) bv[jj] = Bs[k][(tx << 2) + jj];
            #pragma unroll
            for (int i = 0; i < 4; ++i)
                #pragma unroll
                for (int jj = 0; jj < 4; ++jj) acc[i][jj] = fmaf(a[i], bv[jj], acc[i][jj]);
        }
        __syncthreads();
    }
    #pragma unroll
    for (int i = 0; i < 4; ++i) {
        int m = ty + (i << 4);
        #pragma unroll
        for (int jj = 0; jj < 4; ++jj) {
            int g = n0 + (tx << 2) + jj;
            Pb[(size_t)m * NOUTP + g] = acc[i][jj];
        }
    }
}

__global__ void up_reduce(const float* __restrict__ part, const float* __restrict__ ub,
                          float* __restrict__ out) {
    int idx = blockIdx.x * blockDim.x + threadIdx.x;
    if (idx >= BB * NOUT) return;
    int b = idx / NOUT, o = idx % NOUT;
    float acc = ub[o];
    #pragma unroll
    for (int ks = 0; ks < KSPL; ++ks)
        acc += part[((size_t)ks * BB + b) * NOUTP + o];
    out[(size_t)b * NOUT + o] = acc;
}

extern "C" void kernel_launch(void* const* d_in, const int* in_sizes, int n_in,
                              void* d_out, int out_size, void* d_ws, size_t ws_size,
                              hipStream_t stream) {
    const float* x        = (const float*)d_in[0];
    const int*   lens     = (const int*)d_in[1];
    const float* conv_w   = (const float*)d_in[2];
    const float* conv_b   = (const float*)d_in[3];
    const float* wih0     = (const float*)d_in[4];
    const float* wih_rest = (const float*)d_in[5];
    const float* whh      = (const float*)d_in[6];
    const float* bih      = (const float*)d_in[7];
    const float* bhh      = (const float*)d_in[8];
    const float* post_w   = (const float*)d_in[9];
    const float* post_b   = (const float*)d_in[10];
    const float* up_w     = (const float*)d_in[11];
    const float* up_b     = (const float*)d_in[12];
    float* out = (float*)d_out;
    (void)in_sizes; (void)n_in; (void)out_size;

    auto pad = [](size_t v) { return (v + 255) & ~(size_t)255; };
    const size_t szMel   = (size_t)BB * SS * MEL * 2;        // 7.9 MB
    const size_t szH     = (size_t)BB * SS * HH * 2;         // 23.6 MB
    const size_t szSlot  = (size_t)CH * BB * G4P * 2;        // 6.3 MB  [t][b][col] f16
    const size_t szWmf   = (size_t)NL * 48 * NKS * 64 * 16;  // 1.18 MB
    const size_t szWihP  = (size_t)NL * G4P * NKP * 4;
    const size_t szBsP   = (size_t)NL * G4P * 4;
    const size_t szState = (size_t)BB * HH * 4;
    const size_t szLast  = (size_t)BB * HH * 4;
    const size_t szPost  = (size_t)BB * NPOST * 4;
    const size_t szPart  = (size_t)KSPL * BB * NOUTP * 4;

    size_t commonSmall = pad(szWmf) + pad(szWihP) + pad(szBsP) + 2 * NL * pad(szState) +
                         pad(szLast) + pad(szPost) + pad(szPart) + 4096;
    size_t needWF = pad(szMel) + 4 * pad(szH) + 8 * pad(szSlot) + commonSmall;
    int wavefront = (ws_size >= needWF) ? 1 : 0;

    char* wsp = (char*)d_ws;
    size_t off = 0;
    auto alloc = [&](size_t bytes) -> void* {
        void* p = wsp + off;
        off = (off + bytes + 255) & ~(size_t)255;
        return p;
    };

    __half* melF = (__half*)alloc(szMel);
    __half* hbuf[NL];
    if (wavefront) {
        for (int l = 0; l < NL; ++l) hbuf[l] = (__half*)alloc(szH);
    } else {
        __half* p0 = (__half*)alloc(szH);
        __half* p1 = (__half*)alloc(szH);
        hbuf[0] = p0; hbuf[1] = p1; hbuf[2] = p0; hbuf[3] = p1;
    }
    __half* slotDB[NL][2];
    if (wavefront) {
        for (int l = 0; l < NL; ++l) {
            slotDB[l][0] = (__half*)alloc(szSlot);
            slotDB[l][1] = (__half*)alloc(szSlot);
        }
    } else {
        __half* s0 = (__half*)alloc(szSlot);
        for (int l = 0; l < NL; ++l) { slotDB[l][0] = s0; slotDB[l][1] = s0; }
    }
    uint4* wmf = (uint4*)alloc(szWmf);
    unsigned int* wihP = (unsigned int*)alloc(szWihP);
    float* bsP = (float*)alloc(szBsP);
    float* hstates = (float*)alloc(NL * pad(szState));
    float* cstates = (float*)alloc(NL * pad(szState));
    float* lastb = (float*)alloc(szLast);
    float* postb = (float*)alloc(szPost);
    float* partb = (float*)alloc(szPart);
    size_t stStride = pad(szState) / 4;

    prep_wmf<<<(NL * 48 * NKS * 64 + 255) / 256, 256, 0, stream>>>(whh, wmf);
    prep_wihP<<<(NL * G4P * NKP + 255) / 256, 256, 0, stream>>>(wih0, wih_rest, wihP);
    prep_bsumP<<<(NL * G4P + 255) / 256, 256, 0, stream>>>(bih, bhh, bsP);

    {
        __half* m0 = hbuf[0];
        __half* m1 = (__half*)((char*)hbuf[0] + pad(szMel));
        mel_block<float><<<dim3(BB, SS / TT), 256, 0, stream>>>(x, m0, conv_w + 0 * 900, conv_b + 0 * 60);
        mel_block<__half><<<dim3(BB, SS / TT), 256, 0, stream>>>(m0, m1, conv_w + 1 * 900, conv_b + 1 * 60);
        mel_block<__half><<<dim3(BB, SS / TT), 256, 0, stream>>>(m1, melF, conv_w + 2 * 900, conv_b + 2 * 60);
    }

    auto setScan = [&](WaveArgs& wa, int nj, int l, int c) {
        wa.spre[nj] = slotDB[l][c & 1];
        wa.swmf[nj] = wmf + (size_t)l * 48 * NKS * 64;
        wa.shout[nj] = hbuf[l];
        wa.shst[nj] = hstates + (size_t)l * stStride;
        wa.scst[nj] = cstates + (size_t)l * stStride;
        wa.st0[nj] = c * CH;
    };
    auto setGemm = [&](WaveArgs& wa, int nj, int l, int c) {
        wa.gA[nj]  = (l == 0) ? melF : hbuf[l - 1];
        wa.gK[nj]  = (l == 0) ? MEL : HH;
        wa.gKT[nj] = (l == 0) ? 4 : 12;
        wa.gW[nj]  = wihP + (size_t)l * G4P * NKP;
        wa.gbs[nj] = bsP + (size_t)l * G4P;
        wa.gC[nj]  = slotDB[l][c & 1];
        wa.gt0[nj] = c * CH;
    };

    if (wavefront) {
        // 2-skew: wave w runs scan(l, w-1-2l) and gemm(l, w-2l); all deps cross-dispatch.
        int wmax = NCH + 2 * (NL - 1);   // 22
        for (int w = 0; w <= wmax; ++w) {
            WaveArgs wa{};
            int nS = 0, nG = 0;
            for (int l = 0; l < NL; ++l) {
                int cs = w - 1 - 2 * l;
                if (cs >= 0 && cs < NCH) { setScan(wa, nS, l, cs); ++nS; }
                int cg = w - 2 * l;
                if (cg >= 0 && cg < NCH) { setGemm(wa, nG, l, cg); ++nG; }
            }
            wa.nS = nS; wa.nG = nG;
            int grid = nS * 4 + nG * CH * 6;
            if (grid) wave_step<<<grid, 512, 0, stream>>>(wa);
        }
    } else {
        for (int l = 0; l < NL; ++l) {
            for (int c = 0; c < NCH; ++c) {
                WaveArgs wa{};
                setGemm(wa, 0, l, c);
                wa.nS = 0; wa.nG = 1;
                wave_step<<<CH * 6, 512, 0, stream>>>(wa);
                WaveArgs wb{};
                setScan(wb, 0, l, c);
                wb.nS = 1; wb.nG = 0;
                wave_step<<<4, 512, 0, stream>>>(wb);
            }
        }
    }

    gather_last<<<(BB * HH + 255) / 256, 256, 0, stream>>>(hbuf[NL - 1], lens, lastb);
    post_gemm<<<NPOST / 64, 256, 0, stream>>>(lastb, post_w, post_b, postb);
    up_gemm<<<dim3(NOUTP / 64, KSPL), 256, 0, stream>>>(postb, up_w, partb);
    up_reduce<<<(BB * NOUT + 255) / 256, 256, 0, stream>>>(partb, up_b, out);
}

// Round 12
// 2453.076 us; speedup vs baseline: 2.5951x; 2.5951x over previous
//
#include <hip/hip_runtime.h>
#include <hip/hip_fp16.h>

#define BB 64
#define SS 1024
#define MEL 60
#define HH 180
#define G4 720    // 4*H
#define NKS 6     // k-steps of 32 (K padded to 192)
#define KP 192
#define NL 4
#define NPOST 8192
#define NOUT 300
#define NOUTP 320
#define KSPL 16
#define TT 128
#define CH 64
#define NCH (SS / CH)
#define KPAIR 96

typedef _Float16 f16x8 __attribute__((ext_vector_type(8)));
typedef float f32x4 __attribute__((ext_vector_type(4)));

#if defined(__has_builtin)
#if __has_builtin(__builtin_amdgcn_fdot2)
#define HAVE_FDOT2 1
#endif
#endif
#ifndef HAVE_FDOT2
#define HAVE_FDOT2 0
#endif

__device__ __forceinline__ float fdot2u(unsigned int w, unsigned int h, float acc) {
#if HAVE_FDOT2
    typedef _Float16 h2_t __attribute__((ext_vector_type(2)));
    union U { unsigned int u; h2_t v; };
    U a, b;
    a.u = w; b.u = h;
    return __builtin_amdgcn_fdot2(a.v, b.v, acc, false);
#else
    __half2 aw = *reinterpret_cast<const __half2*>(&w);
    __half2 ah = *reinterpret_cast<const __half2*>(&h);
    acc += __half2float(__low2half(aw)) * __half2float(__low2half(ah));
    acc += __half2float(__high2half(aw)) * __half2float(__high2half(ah));
    return acc;
#endif
}

union WU { uint4 u; f16x8 f; };

// ---------------- prep ----------------
// wmf[l][g 48][ks 6][lane 64] = 8 f16: g = q*12 + hg; hid = hg*16 + (lane&15);
// elem j = whh[l][q*180 + hid][k], k = ks*32 + 8*(lane>>4) + j; zero-padded.
// (layout refcheck-verified rounds 9-11)
__global__ void prep_wmf(const float* __restrict__ whh, uint4* __restrict__ wmf) {
    int idx = blockIdx.x * blockDim.x + threadIdx.x;
    int total = NL * 48 * NKS * 64;
    if (idx >= total) return;
    int l = idx / (48 * NKS * 64);
    int r1 = idx % (48 * NKS * 64);
    int g = r1 / (NKS * 64);
    int r2 = r1 % (NKS * 64);
    int ks = r2 / 64, lane = r2 % 64;
    int q = g / 12, hg = g % 12;
    int hid = hg * 16 + (lane & 15);
    unsigned short v[8];
    #pragma unroll
    for (int j = 0; j < 8; ++j) {
        int k = ks * 32 + ((lane >> 4) << 3) + j;
        float f = (hid < HH && k < HH) ? whh[((size_t)l * G4 + q * HH + hid) * HH + k] : 0.f;
        v[j] = __half_as_ushort(__float2half(f));
    }
    uint4 u;
    u.x = (unsigned)v[0] | ((unsigned)v[1] << 16);
    u.y = (unsigned)v[2] | ((unsigned)v[3] << 16);
    u.z = (unsigned)v[4] | ((unsigned)v[5] << 16);
    u.w = (unsigned)v[6] | ((unsigned)v[7] << 16);
    wmf[idx] = u;
}

// wih16: [l][g 720][kp 96] uint = packed f16 pair; zero beyond K  (round-7 verified)
__global__ void prep_wih16(const float* __restrict__ wih0, const float* __restrict__ wih_rest,
                           unsigned int* __restrict__ w) {
    int idx = blockIdx.x * blockDim.x + threadIdx.x;
    int total = NL * G4 * KPAIR;
    if (idx >= total) return;
    int l = idx / (G4 * KPAIR);
    int r = idx % (G4 * KPAIR);
    int g = r / KPAIR, kp = r % KPAIR;
    int K = (l == 0) ? MEL : HH;
    const float* src = (l == 0) ? (wih0 + (size_t)g * MEL)
                                : (wih_rest + ((size_t)(l - 1) * G4 + g) * HH);
    float a = 0.f, b = 0.f;
    if (2 * kp < K) { a = src[2 * kp]; b = src[2 * kp + 1]; }
    __half2 h2 = __floats2half2_rn(a, b);
    w[idx] = *(unsigned int*)&h2;
}

__global__ void prep_bsum(const float* __restrict__ bih, const float* __restrict__ bhh,
                          float* __restrict__ bsum) {
    int idx = blockIdx.x * blockDim.x + threadIdx.x;
    if (idx >= NL * G4) return;
    bsum[idx] = bih[idx] + bhh[idx];
}

// ---------------- mel smooth residual block ----------------
template <typename TIN>
__global__ __launch_bounds__(256) void mel_block(const TIN* __restrict__ in,
                                                 __half* __restrict__ out,
                                                 const float* __restrict__ w,
                                                 const float* __restrict__ bias) {
    __shared__ float xt[TT + 4][MEL];
    __shared__ float ws[900];
    __shared__ float bs[MEL];
    int bb = blockIdx.x;
    int t0 = blockIdx.y * TT;
    int tid = threadIdx.x;
    const TIN* inb = in + (size_t)bb * SS * MEL;
    for (int idx = tid; idx < (TT + 4) * MEL; idx += 256) {
        int tt = idx / MEL, ch = idx % MEL;
        int t = t0 + tt - 2;
        xt[tt][ch] = (t >= 0 && t < SS) ? (float)inb[(size_t)t * MEL + ch] : 0.f;
    }
    for (int idx = tid; idx < 900; idx += 256) ws[idx] = w[idx];
    if (tid < MEL) bs[tid] = bias[(tid % 3) * 20 + tid / 3];
    __syncthreads();
    for (int idx = tid; idx < TT * MEL; idx += 256) {
        int tt = idx / MEL, ch = idx % MEL;
        int i = ch / 3, j = ch % 3;
        int qb = 3 * i + (j - 1);
        float acc = bs[ch];
        #pragma unroll
        for (int c = 0; c < 3; ++c) {
            int q = qb + c;
            if (q >= 0 && q < MEL) {
                const float* wp = ws + ((j * 20 + i) * 3 + c) * 5;
                #pragma unroll
                for (int k = 0; k < 5; ++k) acc += xt[tt + k][q] * wp[k];
            }
        }
        out[(size_t)bb * SS * MEL + (size_t)(t0 + tt) * MEL + ch] =
            __float2half(acc + xt[tt + 2][ch]);
    }
}

// ---------------- f16 input GEMM (multi-job, round-7 verified) ----------------
struct GemmArgs {
    const __half* A[16];
    const unsigned int* W[16];
    const float* bs[16];
    __half* C[16];
    size_t cbs[16];
    int K[16];
    int KT[16];
    int t0[16];
};

__global__ __launch_bounds__(256) void gemm_pre(GemmArgs ga) {
    int j = blockIdx.z;
    int K = ga.K[j], KT = ga.KT[j];
    const __half* Ab = ga.A[j] + ((size_t)blockIdx.x * SS + ga.t0[j]) * K;
    __half* Cb = ga.C[j] + (size_t)blockIdx.x * ga.cbs[j];
    const unsigned int* Wj = ga.W[j];
    const float* bsum = ga.bs[j];
    __shared__ unsigned int A16[8][72];
    __shared__ unsigned int W16[8][72];
    int n0 = blockIdx.y * 64;
    int tid = threadIdx.x;
    int tx = tid & 15, ty = tid >> 4;
    int kpl = tid & 7, mg = tid >> 3;
    float acc[4][4];
    #pragma unroll
    for (int i = 0; i < 4; ++i)
        #pragma unroll
        for (int jn = 0; jn < 4; ++jn) acc[i][jn] = 0.f;

    for (int kt = 0; kt < KT; ++kt) {
        int kp = kt * 8 + kpl;
        #pragma unroll
        for (int r = 0; r < 2; ++r) {
            int m = mg + 32 * r;
            unsigned int av = 0u;
            if (2 * kp < K) av = *(const unsigned int*)(Ab + (size_t)m * K + 2 * kp);
            A16[kpl][m] = av;
            int g = n0 + m;
            W16[kpl][m] = (g < G4) ? Wj[(size_t)g * KPAIR + kp] : 0u;
        }
        __syncthreads();
        #pragma unroll
        for (int k = 0; k < 8; ++k) {
            unsigned int a[4], b[4];
            #pragma unroll
            for (int i = 0; i < 4; ++i) a[i] = A16[k][ty + (i << 4)];
            #pragma unroll
            for (int jn = 0; jn < 4; ++jn) b[jn] = W16[k][(tx << 2) + jn];
            #pragma unroll
            for (int i = 0; i < 4; ++i)
                #pragma unroll
                for (int jn = 0; jn < 4; ++jn) acc[i][jn] = fdot2u(b[jn], a[i], acc[i][jn]);
        }
        __syncthreads();
    }
    int g0 = n0 + (tx << 2);
    if (g0 < G4) {
        #pragma unroll
        for (int i = 0; i < 4; ++i) {
            int m = ty + (i << 4);
            __half2 p0 = __floats2half2_rn(acc[i][0] + bsum[g0], acc[i][1] + bsum[g0 + 1]);
            __half2 p1 = __floats2half2_rn(acc[i][2] + bsum[g0 + 2], acc[i][3] + bsum[g0 + 3]);
            *(__half2*)(Cb + (size_t)m * G4 + g0) = p0;
            *(__half2*)(Cb + (size_t)m * G4 + g0 + 2) = p1;
        }
    }
}

// ---------------- LSTM scan: per-wave all-4-gates MFMA, in-register nonlinearity ----------------
struct ScanArgs {
    const __half* pre[NL];   // [b][CH][720] (pbs = batch stride)
    size_t pbs[NL];
    const uint4* wmf[NL];    // padded 48-group layout
    __half* hout[NL];
    float* hst[NL];
    float* cst[NL];
    int t0[NL];
};

__global__ __launch_bounds__(768) __attribute__((amdgpu_waves_per_eu(3, 3)))
void lstm_scan(ScanArgs sa) {
    int j = blockIdx.x / BB, b = blockIdx.x % BB;
    int tid = threadIdx.x;
    int wv = tid >> 6, lane = tid & 63;
    int r0 = lane >> 4, cl = lane & 15;
    int hid = (wv << 4) + cl;            // 0..191
    int t0 = sa.t0[j];
    const __half* preb = sa.pre[j] + (size_t)b * sa.pbs[j];
    __half* houtb = sa.hout[j] + ((size_t)b * SS + (size_t)t0) * HH;
    float* hstb = sa.hst[j] + b * HH;
    float* cstb = sa.cst[j] + b * HH;
    bool act = (hid < HH);

    __shared__ __align__(16) unsigned short hs[2][KP];   // 768 B, double-buffered h

    // wave wv holds all 4 gates' weights for hid in [16wv, 16wv+16): cg = q*12 + wv
    // 24 uint4 = 96 regs, loaded once per chunk (round-7 budget: fits at 3 waves/EU)
    uint4 wfr[4][NKS];
    {
        const uint4* wm = sa.wmf[j];
        #pragma unroll
        for (int q = 0; q < 4; ++q)
            #pragma unroll
            for (int ks = 0; ks < NKS; ++ks)
                wfr[q][ks] = wm[((q * 12 + wv) * NKS + ks) * 64 + lane];
    }
    #pragma unroll
    for (int q = 0; q < 4; ++q)
        #pragma unroll
        for (int ks = 0; ks < NKS; ++ks)
            asm volatile("" : "+v"(wfr[q][ks].x), "+v"(wfr[q][ks].y),
                              "+v"(wfr[q][ks].z), "+v"(wfr[q][ks].w));

    float c = 0.f, hl = 0.f;
    if (t0 > 0 && act) c = cstb[hid];
    if (tid < KP) {
        float hv = 0.f;
        if (t0 > 0 && tid < HH) hv = hstb[tid];
        hs[0][tid] = __half_as_ushort(__float2half(hv));
    }
    __syncthreads();

    // pre values for this lane's (hid, 4 gates), prefetched one step ahead
    float pc[4] = {0.f, 0.f, 0.f, 0.f};
    if (act) {
        #pragma unroll
        for (int q = 0; q < 4; ++q) pc[q] = __half2float(preb[q * HH + hid]);
    }
    int hoff = r0 << 4;   // byte offset within a 64-B k-step block
    for (int t = 0; t < CH; ++t) {
        float pn[4] = {0.f, 0.f, 0.f, 0.f};
        if (act && t + 1 < CH) {
            const __half* pp = preb + (size_t)(t + 1) * G4;
            #pragma unroll
            for (int q = 0; q < 4; ++q) pn[q] = __half2float(pp[q * HH + hid]);
        }
        const unsigned short* hrow = hs[t & 1];
        f16x8 hf[NKS];
        #pragma unroll
        for (int ks = 0; ks < NKS; ++ks) {
            WU hu;
            hu.u = *(const uint4*)((const char*)hrow + (ks << 6) + hoff);
            hf[ks] = hu.f;
        }
        f32x4 a0 = {0.f,0.f,0.f,0.f}, a1 = a0, a2 = a0, a3 = a0;
        #pragma unroll
        for (int ks = 0; ks < NKS; ++ks) {
            WU w0, w1, w2, w3;
            w0.u = wfr[0][ks]; w1.u = wfr[1][ks]; w2.u = wfr[2][ks]; w3.u = wfr[3][ks];
            a0 = __builtin_amdgcn_mfma_f32_16x16x32_f16(hf[ks], w0.f, a0, 0, 0, 0);
            a1 = __builtin_amdgcn_mfma_f32_16x16x32_f16(hf[ks], w1.f, a1, 0, 0, 0);
            a2 = __builtin_amdgcn_mfma_f32_16x16x32_f16(hf[ks], w2.f, a2, 0, 0, 0);
            a3 = __builtin_amdgcn_mfma_f32_16x16x32_f16(hf[ks], w3.f, a3, 0, 0, 0);
        }
        // rows of D are replicated (A rows identical) -> a?[0] is this lane's value at col hid
        float gi = a0[0] + pc[0];
        float gf = a1[0] + pc[1];
        float gg = a2[0] + pc[2];
        float go = a3[0] + pc[3];
        float si = 1.f / (1.f + __expf(-gi));
        float sf = 1.f / (1.f + __expf(-gf));
        float so = 1.f / (1.f + __expf(-go));
        float tg = 1.f - 2.f / (__expf(2.f * gg) + 1.f);
        c = sf * c + si * tg;
        float hn = so * (1.f - 2.f / (__expf(2.f * c) + 1.f));
        if (!act) hn = 0.f;
        hl = hn;
        __half hh = __float2half(hn);
        if (r0 == 0) {
            hs[(t + 1) & 1][hid] = __half_as_ushort(hh);
            if (act) houtb[(size_t)t * HH + hid] = hh;
        }
        __syncthreads();
        #pragma unroll
        for (int q = 0; q < 4; ++q) pc[q] = pn[q];
    }
    if (r0 == 0 && act) {
        cstb[hid] = c;
        hstb[hid] = hl;
    }
}

// ---------------- epilogue ----------------
__global__ void gather_last(const __half* __restrict__ hfin, const int* __restrict__ lens,
                            float* __restrict__ last) {
    int idx = blockIdx.x * blockDim.x + threadIdx.x;
    if (idx >= BB * HH) return;
    int b = idx / HH, d = idx % HH;
    int t = lens[b] - 1;
    t = t < 0 ? 0 : (t > SS - 1 ? SS - 1 : t);
    last[idx] = __half2float(hfin[((size_t)b * SS + t) * HH + d]);
}

__global__ __launch_bounds__(256) void post_gemm(const float* __restrict__ A,
                                                 const float* __restrict__ Bw,
                                                 const float* __restrict__ pb,
                                                 float* __restrict__ Cb) {
    __shared__ float As[16][68];
    __shared__ float Bs[16][68];
    int n0 = blockIdx.x * 64;
    int tid = threadIdx.x;
    int kk = tid & 15, q = tid >> 4;
    int tx = tid & 15, ty = tid >> 4;
    float acc[4][4];
    #pragma unroll
    for (int i = 0; i < 4; ++i)
        #pragma unroll
        for (int jj = 0; jj < 4; ++jj) acc[i][jj] = 0.f;
    for (int kt = 0; kt < 12; ++kt) {
        int kidx = kt * 16 + kk;
        bool kval = kidx < HH;
        #pragma unroll
        for (int r = 0; r < 4; ++r)
            As[kk][q + (r << 4)] = kval ? A[(size_t)(q + (r << 4)) * HH + kidx] : 0.f;
        #pragma unroll
        for (int r = 0; r < 4; ++r)
            Bs[kk][q + (r << 4)] = kval ? Bw[(size_t)(n0 + q + (r << 4)) * HH + kidx] : 0.f;
        __syncthreads();
        #pragma unroll
        for (int k = 0; k < 16; ++k) {
            float a[4], bv[4];
            #pragma unroll
            for (int i = 0; i < 4; ++i) a[i] = As[k][ty + (i << 4)];
            #pragma unroll
            for (int jj = 0; jj < 4; ++jj) bv[jj] = Bs[k][(tx << 2) + jj];
            #pragma unroll
            for (int i = 0; i < 4; ++i)
                #pragma unroll
                for (int jj = 0; jj < 4; ++jj) acc[i][jj] = fmaf(a[i], bv[jj], acc[i][jj]);
        }
        __syncthreads();
    }
    #pragma unroll
    for (int i = 0; i < 4; ++i) {
        int m = ty + (i << 4);
        #pragma unroll
        for (int jj = 0; jj < 4; ++jj) {
            int g = n0 + (tx << 2) + jj;
            float v = acc[i][jj] + pb[g];
            Cb[(size_t)m * NPOST + g] = v > 0.f ? v : 0.01f * v;
        }
    }
}

__global__ __launch_bounds__(256) void up_gemm(const float* __restrict__ A,
                                               const float* __restrict__ Bw,
                                               float* __restrict__ part) {
    __shared__ float As[16][68];
    __shared__ float Bs[16][68];
    int n0 = blockIdx.x * 64;
    int k0 = blockIdx.y * (NPOST / KSPL);
    float* Pb = part + (size_t)blockIdx.y * BB * NOUTP;
    int tid = threadIdx.x;
    int kk = tid & 15, q = tid >> 4;
    int tx = tid & 15, ty = tid >> 4;
    float acc[4][4];
    #pragma unroll
    for (int i = 0; i < 4; ++i)
        #pragma unroll
        for (int jj = 0; jj < 4; ++jj) acc[i][jj] = 0.f;
    for (int kt = 0; kt < (NPOST / KSPL) / 16; ++kt) {
        int kidx = k0 + kt * 16 + kk;
        #pragma unroll
        for (int r = 0; r < 4; ++r)
            As[kk][q + (r << 4)] = A[(size_t)(q + (r << 4)) * NPOST + kidx];
        #pragma unroll
        for (int r = 0; r < 4; ++r) {
            int g = n0 + q + (r << 4);
            Bs[kk][q + (r << 4)] = (g < NOUT) ? Bw[(size_t)g * NPOST + kidx] : 0.f;
        }
        __syncthreads();
        #pragma unroll
        for (int k = 0; k < 16; ++k) {
            float a[4], bv[4];
            #pragma unroll
            for (int i = 0; i < 4; ++i) a[i] = As[k][ty + (i << 4)];
            #pragma unroll
            for (int jj = 0; jj < 4; ++jj) bv[jj] = Bs[k][(tx << 2) + jj];
            #pragma unroll
            for (int i = 0; i < 4; ++i)
                #pragma unroll
                for (int jj = 0; jj < 4; ++jj) acc[i][jj] = fmaf(a[i], bv[jj], acc[i][jj]);
        }
        __syncthreads();
    }
    #pragma unroll
    for (int i = 0; i < 4; ++i) {
        int m = ty + (i << 4);
        #pragma unroll
        for (int jj = 0; jj < 4; ++jj) {
            int g = n0 + (tx << 2) + jj;
            Pb[(size_t)m * NOUTP + g] = acc[i][jj];
        }
    }
}

__global__ void up_reduce(const float* __restrict__ part, const float* __restrict__ ub,
                          float* __restrict__ out) {
    int idx = blockIdx.x * blockDim.x + threadIdx.x;
    if (idx >= BB * NOUT) return;
    int b = idx / NOUT, o = idx % NOUT;
    float acc = ub[o];
    #pragma unroll
    for (int ks = 0; ks < KSPL; ++ks)
        acc += part[((size_t)ks * BB + b) * NOUTP + o];
    out[(size_t)b * NOUT + o] = acc;
}

extern "C" void kernel_launch(void* const* d_in, const int* in_sizes, int n_in,
                              void* d_out, int out_size, void* d_ws, size_t ws_size,
                              hipStream_t stream) {
    const float* x        = (const float*)d_in[0];
    const int*   lens     = (const int*)d_in[1];
    const float* conv_w   = (const float*)d_in[2];
    const float* conv_b   = (const float*)d_in[3];
    const float* wih0     = (const float*)d_in[4];
    const float* wih_rest = (const float*)d_in[5];
    const float* whh      = (const float*)d_in[6];
    const float* bih      = (const float*)d_in[7];
    const float* bhh      = (const float*)d_in[8];
    const float* post_w   = (const float*)d_in[9];
    const float* post_b   = (const float*)d_in[10];
    const float* up_w     = (const float*)d_in[11];
    const float* up_b     = (const float*)d_in[12];
    float* out = (float*)d_out;
    (void)in_sizes; (void)n_in; (void)out_size;

    auto pad = [](size_t v) { return (v + 255) & ~(size_t)255; };
    const size_t szMel   = (size_t)BB * SS * MEL * 2;
    const size_t szH     = (size_t)BB * SS * HH * 2;
    const size_t szPre0  = (size_t)BB * SS * G4 * 2;          // 94.4 MB (full layer-0 pre)
    const size_t szSlot  = (size_t)BB * CH * G4 * 2;          // 5.9 MB
    const size_t szWmf   = (size_t)NL * 48 * NKS * 64 * 16;   // 1.18 MB
    const size_t szWih   = (size_t)NL * G4 * KPAIR * 4;
    const size_t szBsum  = (size_t)NL * G4 * 4;
    const size_t szState = (size_t)NL * BB * HH * 4;
    const size_t szLast  = (size_t)BB * HH * 4;
    const size_t szPost  = (size_t)BB * NPOST * 4;
    const size_t szPart  = (size_t)KSPL * BB * NOUTP * 4;

    size_t commonSmall = pad(szWmf) + pad(szWih) + pad(szBsum) + 2 * pad(szState) +
                         pad(szLast) + pad(szPost) + pad(szPart) + 4096;
    size_t need1 = pad(szMel) + 4 * pad(szH) + pad(szPre0) + 3 * pad(szSlot) + commonSmall;
    size_t need2 = pad(szMel) + 4 * pad(szH) + 4 * pad(szSlot) + commonSmall;
    int tier = (ws_size >= need1) ? 1 : ((ws_size >= need2) ? 2 : 3);

    char* wsp = (char*)d_ws;
    size_t off = 0;
    auto alloc = [&](size_t bytes) -> void* {
        void* p = wsp + off;
        off = (off + bytes + 255) & ~(size_t)255;
        return p;
    };

    __half* melF = (__half*)alloc(szMel);
    __half* hbuf[NL];
    if (tier <= 2) {
        for (int l = 0; l < NL; ++l) hbuf[l] = (__half*)alloc(szH);
    } else {
        __half* p0 = (__half*)alloc(szH);
        __half* p1 = (__half*)alloc(szH);
        hbuf[0] = p0; hbuf[1] = p1; hbuf[2] = p0; hbuf[3] = p1;
    }
    __half* pre0 = nullptr;
    __half* slot[NL] = {nullptr, nullptr, nullptr, nullptr};
    if (tier == 1) {
        pre0 = (__half*)alloc(szPre0);
        for (int l = 1; l < NL; ++l) slot[l] = (__half*)alloc(szSlot);
    } else if (tier == 2) {
        for (int l = 0; l < NL; ++l) slot[l] = (__half*)alloc(szSlot);
    } else {
        slot[0] = (__half*)alloc(szSlot);
        for (int l = 1; l < NL; ++l) slot[l] = slot[0];
    }
    uint4* wmf = (uint4*)alloc(szWmf);
    unsigned int* wih16 = (unsigned int*)alloc(szWih);
    float* bsum  = (float*)alloc(szBsum);
    float* hstates = (float*)alloc(szState);
    float* cstates = (float*)alloc(szState);
    float* lastb = (float*)alloc(szLast);
    float* postb = (float*)alloc(szPost);
    float* partb = (float*)alloc(szPart);

    prep_wmf<<<(NL * 48 * NKS * 64 + 255) / 256, 256, 0, stream>>>(whh, wmf);
    prep_wih16<<<(NL * G4 * KPAIR + 255) / 256, 256, 0, stream>>>(wih0, wih_rest, wih16);
    prep_bsum<<<(NL * G4 + 255) / 256, 256, 0, stream>>>(bih, bhh, bsum);

    {
        __half* m0 = hbuf[0];
        __half* m1 = (__half*)((char*)hbuf[0] + pad(szMel));
        mel_block<float><<<dim3(BB, SS / TT), 256, 0, stream>>>(x, m0, conv_w + 0 * 900, conv_b + 0 * 60);
        mel_block<__half><<<dim3(BB, SS / TT), 256, 0, stream>>>(m0, m1, conv_w + 1 * 900, conv_b + 1 * 60);
        mel_block<__half><<<dim3(BB, SS / TT), 256, 0, stream>>>(m1, melF, conv_w + 2 * 900, conv_b + 2 * 60);
    }

    auto setGemmJob = [&](GemmArgs& ga, int nj, int l, int c) {
        ga.A[nj]  = (l == 0) ? melF : hbuf[l - 1];
        ga.K[nj]  = (l == 0) ? MEL : HH;
        ga.KT[nj] = (l == 0) ? 4 : 12;
        ga.W[nj]  = wih16 + (size_t)l * G4 * KPAIR;
        ga.bs[nj] = bsum + l * G4;
        if (tier == 1 && l == 0) {
            ga.C[nj] = pre0 + (size_t)c * CH * G4;
            ga.cbs[nj] = (size_t)SS * G4;
        } else {
            ga.C[nj] = slot[l];
            ga.cbs[nj] = (size_t)CH * G4;
        }
        ga.t0[nj] = c * CH;
    };
    auto setScanJob = [&](ScanArgs& sa, int nj, int l, int c) {
        if (tier == 1 && l == 0) {
            sa.pre[nj] = pre0 + (size_t)c * CH * G4;
            sa.pbs[nj] = (size_t)SS * G4;
        } else {
            sa.pre[nj] = slot[l];
            sa.pbs[nj] = (size_t)CH * G4;
        }
        sa.wmf[nj]  = wmf + (size_t)l * 48 * NKS * 64;
        sa.hout[nj] = hbuf[l];
        sa.hst[nj]  = hstates + (size_t)l * BB * HH;
        sa.cst[nj]  = cstates + (size_t)l * BB * HH;
        sa.t0[nj]   = c * CH;
    };

    if (tier <= 2) {
        if (tier == 1) {
            GemmArgs ga{};
            for (int c = 0; c < NCH; ++c) setGemmJob(ga, c, 0, c);
            gemm_pre<<<dim3(BB, 12, NCH), 256, 0, stream>>>(ga);
        }
        int lmin = (tier == 1) ? 1 : 0;
        for (int w = 0; w < NCH + NL - 1; ++w) {
            GemmArgs ga{};
            int njg = 0;
            for (int l = lmin; l < NL; ++l) {
                int c = w - l;
                if (c < 0 || c >= NCH) continue;
                setGemmJob(ga, njg++, l, c);
            }
            if (njg) gemm_pre<<<dim3(BB, 12, njg), 256, 0, stream>>>(ga);
            ScanArgs sa{};
            int njs = 0;
            for (int l = 0; l < NL; ++l) {
                int c = w - l;
                if (c < 0 || c >= NCH) continue;
                setScanJob(sa, njs++, l, c);
            }
            if (njs) lstm_scan<<<dim3(njs * BB), 768, 0, stream>>>(sa);
        }
    } else {
        for (int l = 0; l < NL; ++l) {
            for (int c = 0; c < NCH; ++c) {
                GemmArgs ga{}; ScanArgs sa{};
                setGemmJob(ga, 0, l, c);
                gemm_pre<<<dim3(BB, 12, 1), 256, 0, stream>>>(ga);
                setScanJob(sa, 0, l, c);
                lstm_scan<<<dim3(BB), 768, 0, stream>>>(sa);
            }
        }
    }

    gather_last<<<(BB * HH + 255) / 256, 256, 0, stream>>>(hbuf[NL - 1], lens, lastb);
    post_gemm<<<NPOST / 64, 256, 0, stream>>>(lastb, post_w, post_b, postb);
    up_gemm<<<dim3(NOUTP / 64, KSPL), 256, 0, stream>>>(postb, up_w, partb);
    up_reduce<<<(BB * NOUT + 255) / 256, 256, 0, stream>>>(partb, up_b, out);
}